// Round 3
// baseline (484.362 us; speedup 1.0000x reference)
//
#include <hip/hip_runtime.h>
#include <hip/hip_bf16.h>

typedef unsigned short ushort_t;
typedef __bf16 bf16x8 __attribute__((ext_vector_type(8)));
typedef float f32x4 __attribute__((ext_vector_type(4)));
typedef unsigned short us8 __attribute__((ext_vector_type(8)));

#define HW 16384
#define CDIM 192
#define QKVC 576

static __device__ __forceinline__ float b2f(unsigned short u) {
    union { unsigned int i; float f; } cv; cv.i = ((unsigned int)u) << 16; return cv.f;
}
static __device__ __forceinline__ unsigned short f2b(float f) {
    union { __bf16 h; unsigned short u; } cv; cv.h = (__bf16)f; return cv.u;
}

// ---------------------------------------------------------------------------
// K1: depthwise 3x3 (fp32) on x + unbiased variance over HxW per (b,c)
// plane staged in LDS fp32 with +4 row pad (bank spread) + zero row
// ---------------------------------------------------------------------------
__global__ __launch_bounds__(256) void k_dwvar(const float* __restrict__ x,
                                               const float* __restrict__ wdw,
                                               float* __restrict__ var) {
    __shared__ __align__(16) float pl[128 * 132 + 132];   // rows stride 132, zero row at 16896
    __shared__ float red[8];
    int bc = blockIdx.x;                // b*192 + c
    int c = bc % CDIM;
    const float* xp = x + (size_t)bc * HW;
    int t = threadIdx.x;
#pragma unroll
    for (int i = 0; i < 16; ++i) {
        int gi = t + i * 256;           // float4 index [0,4096)
        int y = gi >> 5, xq = (gi & 31) << 2;
        *(f32x4*)&pl[y * 132 + xq] = *(const f32x4*)&xp[gi * 4];
    }
    if (t < 33) { f32x4 zz = {0.f, 0.f, 0.f, 0.f}; *(f32x4*)&pl[16896 + t * 4] = zz; }
    float w[9];
#pragma unroll
    for (int j = 0; j < 9; ++j) w[j] = wdw[c * 9 + j];
    __syncthreads();

    int y = t >> 1, xs = (t & 1) * 64;
    int yb0 = (y > 0)   ? (y - 1) * 132 : 16896;
    int yb1 = y * 132;
    int yb2 = (y < 127) ? (y + 1) * 132 : 16896;
    float l0 = 0.f, l1 = 0.f, l2 = 0.f;
    if (xs != 0) { l0 = pl[yb0 + 63]; l1 = pl[yb1 + 63]; l2 = pl[yb2 + 63]; }
    float s1 = 0.f, s2 = 0.f;
#pragma unroll
    for (int g = 0; g < 8; ++g) {
        int x0 = xs + g * 8;
        float e0[10], e1[10], e2[10];
        e0[0] = l0; e1[0] = l1; e2[0] = l2;
        f32x4 a0 = *(const f32x4*)&pl[yb0 + x0], b0 = *(const f32x4*)&pl[yb0 + x0 + 4];
        f32x4 a1 = *(const f32x4*)&pl[yb1 + x0], b1 = *(const f32x4*)&pl[yb1 + x0 + 4];
        f32x4 a2 = *(const f32x4*)&pl[yb2 + x0], b2 = *(const f32x4*)&pl[yb2 + x0 + 4];
#pragma unroll
        for (int j = 0; j < 4; ++j) {
            e0[1 + j] = a0[j]; e0[5 + j] = b0[j];
            e1[1 + j] = a1[j]; e1[5 + j] = b1[j];
            e2[1 + j] = a2[j]; e2[5 + j] = b2[j];
        }
        float r0 = 0.f, r1 = 0.f, r2 = 0.f;
        if (x0 + 8 < 128) { r0 = pl[yb0 + x0 + 8]; r1 = pl[yb1 + x0 + 8]; r2 = pl[yb2 + x0 + 8]; }
        e0[9] = r0; e1[9] = r1; e2[9] = r2;
#pragma unroll
        for (int j = 0; j < 8; ++j) {
            float o = e0[j] * w[0] + e0[j + 1] * w[1] + e0[j + 2] * w[2]
                    + e1[j] * w[3] + e1[j + 1] * w[4] + e1[j + 2] * w[5]
                    + e2[j] * w[6] + e2[j + 1] * w[7] + e2[j + 2] * w[8];
            s1 += o; s2 += o * o;
        }
        l0 = e0[8]; l1 = e1[8]; l2 = e2[8];
    }
#pragma unroll
    for (int off = 32; off; off >>= 1) { s1 += __shfl_xor(s1, off); s2 += __shfl_xor(s2, off); }
    int wv = t >> 6;
    if ((t & 63) == 0) { red[wv * 2] = s1; red[wv * 2 + 1] = s2; }
    __syncthreads();
    if (t == 0) {
        float S1 = red[0] + red[2] + red[4] + red[6];
        float S2 = red[1] + red[3] + red[5] + red[7];
        var[bc] = (S2 - S1 * S1 * (1.0f / 16384.f)) * (1.0f / 16383.f);
    }
}

// ---------------------------------------------------------------------------
// K3: depthwise 3x3 on qkv planes (bf16 in/out, fp32 math/weights) + sum-sq
// LDS rows stride 136 bf16 (+8 pad) + zero row at 17408
// ---------------------------------------------------------------------------
__global__ __launch_bounds__(256) void k_dwqkv(const ushort_t* __restrict__ qkvraw,
                                               const float* __restrict__ wqd,
                                               ushort_t* __restrict__ qkvd,
                                               float* __restrict__ ssq) {
    __shared__ __align__(16) ushort_t pl[128 * 136 + 136];
    __shared__ float red[4];
    int bo = blockIdx.x;               // b*576 + o
    int o = bo % QKVC, b = bo / QKVC;
    const ushort_t* xp = qkvraw + (size_t)bo * HW;
    ushort_t* op = qkvd + (size_t)bo * HW;
    int t = threadIdx.x;
#pragma unroll
    for (int i = 0; i < 8; ++i) {
        int gi = t + i * 256;           // us8 index [0,2048)
        int y = gi >> 4, xo = (gi & 15) * 8;
        *(us8*)&pl[y * 136 + xo] = *(const us8*)&xp[gi * 8];
    }
    if (t < 17) { us8 zz = {}; *(us8*)&pl[17408 + t * 8] = zz; }
    float w[9];
#pragma unroll
    for (int j = 0; j < 9; ++j) w[j] = wqd[o * 9 + j];
    __syncthreads();

    int y = t >> 1, xs = (t & 1) * 64;
    int yb0 = (y > 0)   ? (y - 1) * 136 : 17408;
    int yb1 = y * 136;
    int yb2 = (y < 127) ? (y + 1) * 136 : 17408;
    float l0 = 0.f, l1 = 0.f, l2 = 0.f;
    if (xs != 0) { l0 = b2f(pl[yb0 + 63]); l1 = b2f(pl[yb1 + 63]); l2 = b2f(pl[yb2 + 63]); }
    float s2 = 0.f;
#pragma unroll
    for (int g = 0; g < 8; ++g) {
        int x0 = xs + g * 8;
        us8 v0 = *(const us8*)&pl[yb0 + x0];
        us8 v1 = *(const us8*)&pl[yb1 + x0];
        us8 v2 = *(const us8*)&pl[yb2 + x0];
        float r0 = 0.f, r1 = 0.f, r2 = 0.f;
        if (x0 + 8 < 128) { r0 = b2f(pl[yb0 + x0 + 8]); r1 = b2f(pl[yb1 + x0 + 8]); r2 = b2f(pl[yb2 + x0 + 8]); }
        float e0[10], e1[10], e2[10];
        e0[0] = l0; e1[0] = l1; e2[0] = l2;
#pragma unroll
        for (int j = 0; j < 8; ++j) { e0[j + 1] = b2f(v0[j]); e1[j + 1] = b2f(v1[j]); e2[j + 1] = b2f(v2[j]); }
        e0[9] = r0; e1[9] = r1; e2[9] = r2;
        us8 ob;
#pragma unroll
        for (int j = 0; j < 8; ++j) {
            float ov = e0[j] * w[0] + e0[j + 1] * w[1] + e0[j + 2] * w[2]
                     + e1[j] * w[3] + e1[j + 1] * w[4] + e1[j + 2] * w[5]
                     + e2[j] * w[6] + e2[j + 1] * w[7] + e2[j + 2] * w[8];
            unsigned short bits = f2b(ov);
            ob[j] = bits;
            float rv = b2f(bits);
            s2 += rv * rv;
        }
        *(us8*)&op[(size_t)y * 128 + x0] = ob;
        l0 = e0[8]; l1 = e1[8]; l2 = e2[8];
    }
    if (o < 2 * CDIM) {
#pragma unroll
        for (int off = 32; off; off >>= 1) s2 += __shfl_xor(s2, off);
        int wv = t >> 6;
        if ((t & 63) == 0) red[wv] = s2;
        __syncthreads();
        if (t == 0) ssq[b * 384 + o] = red[0] + red[1] + red[2] + red[3];
    }
}

// ---------------------------------------------------------------------------
// GEMM: C[b] = A[b] (MxK, row-major) * B[b] (KxN, N contiguous), fp32 accum
// dtypes per template flags (1=fp32, 0=bf16); MFMA inputs bf16 (cast at stage)
// BM=64 BN=128 BK=32; 4 waves; mfma 16x16x32 bf16; XOR-swizzled Bs transpose
// ---------------------------------------------------------------------------
template<int AF, int BF, int CF>
__global__ __launch_bounds__(256) void k_gemm(const void* __restrict__ Av, long sAb,
                                              const void* __restrict__ Bv, long sBb,
                                              void* __restrict__ Cv, long sCb, int K) {
    __shared__ __align__(16) ushort_t As[64 * 32];
    __shared__ __align__(16) ushort_t Bs[128 * 32];
    int t = threadIdx.x;
    int wv = t >> 6, lane = t & 63, quad = lane >> 4, l15 = lane & 15;
    size_t aoff = (size_t)blockIdx.z * sAb + (size_t)blockIdx.y * 64 * K;
    size_t boff = (size_t)blockIdx.z * sBb + (size_t)blockIdx.x * 128;
    size_t coff = (size_t)blockIdx.z * sCb + (size_t)blockIdx.y * 64 * HW + (size_t)blockIdx.x * 128;
    f32x4 acc[8] = {};
    int arow = t >> 2, acg = t & 3;
    int bkr = t >> 3, bn0 = (t & 7) * 16;
    int kb = bkr >> 3, klo = bkr & 7, bswz = t & 3;
    int kcol = ((kb ^ bswz) << 3) + klo;
    for (int kk = 0; kk < K; kk += 32) {
        if (AF) {
            const float* Ap = (const float*)Av + aoff;
            f32x4 a0 = *(const f32x4*)&Ap[(size_t)arow * K + kk + acg * 8];
            f32x4 a1 = *(const f32x4*)&Ap[(size_t)arow * K + kk + acg * 8 + 4];
            us8 av;
#pragma unroll
            for (int e = 0; e < 4; ++e) { av[e] = f2b(a0[e]); av[4 + e] = f2b(a1[e]); }
            *(us8*)&As[arow * 32 + acg * 8] = av;
        } else {
            const ushort_t* Ap = (const ushort_t*)Av + aoff;
            *(uint4*)&As[arow * 32 + acg * 8] = *(const uint4*)&Ap[(size_t)arow * K + kk + acg * 8];
        }
        ushort_t bt[16];
        if (BF) {
            const float* Bp = (const float*)Bv + boff;
            const float* rp = &Bp[(size_t)(kk + bkr) * HW + bn0];
            f32x4 f0 = *(const f32x4*)rp, f1 = *(const f32x4*)(rp + 4);
            f32x4 f2v = *(const f32x4*)(rp + 8), f3 = *(const f32x4*)(rp + 12);
#pragma unroll
            for (int e = 0; e < 4; ++e) {
                bt[e] = f2b(f0[e]); bt[4 + e] = f2b(f1[e]);
                bt[8 + e] = f2b(f2v[e]); bt[12 + e] = f2b(f3[e]);
            }
        } else {
            const ushort_t* Bp = (const ushort_t*)Bv + boff;
            us8 t0 = *(const us8*)&Bp[(size_t)(kk + bkr) * HW + bn0];
            us8 t1 = *(const us8*)&Bp[(size_t)(kk + bkr) * HW + bn0 + 8];
#pragma unroll
            for (int e = 0; e < 8; ++e) { bt[e] = t0[e]; bt[8 + e] = t1[e]; }
        }
#pragma unroll
        for (int e = 0; e < 8; ++e) {
            Bs[(bn0 + e) * 32 + kcol] = bt[e];
            Bs[(bn0 + 8 + e) * 32 + kcol] = bt[8 + e];
        }
        __syncthreads();
        bf16x8 af = *(const bf16x8*)&As[(wv * 16 + l15) * 32 + quad * 8];
#pragma unroll
        for (int tc = 0; tc < 8; ++tc) {
            int kb2 = quad ^ (tc & 3);
            bf16x8 bfr = *(const bf16x8*)&Bs[(tc * 16 + l15) * 32 + kb2 * 8];
            acc[tc] = __builtin_amdgcn_mfma_f32_16x16x32_bf16(af, bfr, acc[tc], 0, 0, 0);
        }
        __syncthreads();
    }
#pragma unroll
    for (int tc = 0; tc < 8; ++tc)
#pragma unroll
        for (int r = 0; r < 4; ++r) {
            int row = wv * 16 + quad * 4 + r;
            size_t idx = coff + (size_t)row * HW + tc * 16 + l15;
            if (CF) ((float*)Cv)[idx] = acc[tc][r];
            else    ((ushort_t*)Cv)[idx] = f2b(acc[tc][r]);
        }
}

// ---------------------------------------------------------------------------
// K4: Gram G[b,h] = q . k^T (24x24, K=16384), LDS-staged, mfma, atomic combine
// ---------------------------------------------------------------------------
__global__ __launch_bounds__(256) void k_gram(const ushort_t* __restrict__ qkvd,
                                              float* __restrict__ G) {
    __shared__ __align__(16) ushort_t qs[24 * 264];
    __shared__ __align__(16) ushort_t ks[24 * 264];
    int bh = blockIdx.y;
    int b = bh >> 3, h = bh & 7;
    int t = threadIdx.x, wv = t >> 6, lane = t & 63, quad = lane >> 4, l15 = lane & 15;
    const ushort_t* qb = qkvd + (size_t)b * 9437184 + (size_t)(h * 24) * HW;
    const ushort_t* kp = qb + (size_t)CDIM * HW;
    f32x4 a00 = {}, a01 = {}, a10 = {}, a11 = {};
    bf16x8 z = {};
    bool hi = (l15 < 8);
    int kbase0 = blockIdx.x * 2048;
    for (int sub = 0; sub < 8; ++sub) {
        int kbase = kbase0 + sub * 256;
#pragma unroll
        for (int j = 0; j < 3; ++j) {
            int gi = t + j * 256;       // [0,768)
            int row = gi >> 5, c8 = (gi & 31) * 8;
            *(us8*)&qs[row * 264 + c8] = *(const us8*)&qb[(size_t)row * HW + kbase + c8];
            *(us8*)&ks[row * 264 + c8] = *(const us8*)&kp[(size_t)row * HW + kbase + c8];
        }
        __syncthreads();
#pragma unroll
        for (int s = 0; s < 2; ++s) {
            int ko = (wv * 2 + s) * 32 + quad * 8;
            bf16x8 qa0 = *(const bf16x8*)&qs[l15 * 264 + ko];
            bf16x8 qa1 = hi ? *(const bf16x8*)&qs[(16 + l15) * 264 + ko] : z;
            bf16x8 kb0 = *(const bf16x8*)&ks[l15 * 264 + ko];
            bf16x8 kb1 = hi ? *(const bf16x8*)&ks[(16 + l15) * 264 + ko] : z;
            a00 = __builtin_amdgcn_mfma_f32_16x16x32_bf16(qa0, kb0, a00, 0, 0, 0);
            a01 = __builtin_amdgcn_mfma_f32_16x16x32_bf16(qa0, kb1, a01, 0, 0, 0);
            a10 = __builtin_amdgcn_mfma_f32_16x16x32_bf16(qa1, kb0, a10, 0, 0, 0);
            a11 = __builtin_amdgcn_mfma_f32_16x16x32_bf16(qa1, kb1, a11, 0, 0, 0);
        }
        __syncthreads();
    }
    float* Gp = G + (size_t)bh * 576;
#pragma unroll
    for (int r = 0; r < 4; ++r) {
        int r0 = quad * 4 + r, r1 = 16 + quad * 4 + r;
        int c0 = l15, c1 = 16 + l15;
        atomicAdd(&Gp[r0 * 24 + c0], a00[r]);
        if (c1 < 24) atomicAdd(&Gp[r0 * 24 + c1], a01[r]);
        if (r1 < 24) atomicAdd(&Gp[r1 * 24 + c0], a10[r]);
        if (r1 < 24 && c1 < 24) atomicAdd(&Gp[r1 * 24 + c1], a11[r]);
    }
}

// ---------------------------------------------------------------------------
// K5: softmax(P) per (b,h) and Weff[b] = W_proj * blockdiag(P)  (Weff bf16)
// ---------------------------------------------------------------------------
__global__ __launch_bounds__(256) void k_smweff(const float* __restrict__ G,
                                                const float* __restrict__ ssq,
                                                const float* __restrict__ var,
                                                const float* __restrict__ wproj,
                                                const float* __restrict__ temp,
                                                const float* __restrict__ resc,
                                                ushort_t* __restrict__ Weff) {
    int b = blockIdx.x, t = threadIdx.x;
    __shared__ float P[8 * 24 * 24];
    __shared__ float snq[192], snk[192];
    if (t < 192) {
        snq[t] = fmaxf(sqrtf(ssq[b * 384 + t]), 1e-12f);
        snk[t] = fmaxf(sqrtf(ssq[b * 384 + 192 + t]), 1e-12f);
    }
    __syncthreads();
    if (t < 192) {
        int h = t / 24, c = t % 24;
        float tmpv = temp[h];
        float dvar = resc[h] * var[b * 192 + t];
        const float* Gp = G + (size_t)(b * 8 + h) * 576 + c * 24;
        float inq = tmpv / snq[t];
        float lg[24]; float mx = -1e30f;
#pragma unroll
        for (int d = 0; d < 24; ++d) {
            float v = Gp[d] * inq / snk[h * 24 + d];
            if (d == c) v += dvar;
            lg[d] = v; mx = fmaxf(mx, v);
        }
        float sum = 0.f;
#pragma unroll
        for (int d = 0; d < 24; ++d) { float e = __expf(lg[d] - mx); lg[d] = e; sum += e; }
        float inv = 1.f / sum;
#pragma unroll
        for (int d = 0; d < 24; ++d) P[(h * 24 + c) * 24 + d] = lg[d] * inv;
    }
    __syncthreads();
    for (int i = 0; i < 144; ++i) {
        int idx = t + i * 256;
        int co = idx / 192, hd = idx % 192;
        int h2 = hd / 24, d = hd % 24;
        float a = 0.f;
#pragma unroll
        for (int c2 = 0; c2 < 24; ++c2)
            a += wproj[co * 192 + h2 * 24 + c2] * P[(h2 * 24 + c2) * 24 + d];
        Weff[(size_t)b * 36864 + idx] = f2b(a);
    }
}

// ---------------------------------------------------------------------------
extern "C" void kernel_launch(void* const* d_in, const int* in_sizes, int n_in,
                              void* d_out, int out_size, void* d_ws, size_t ws_size,
                              hipStream_t stream) {
    const float* x      = (const float*)d_in[0];
    const float* wdw    = (const float*)d_in[1];
    const float* wqkv   = (const float*)d_in[2];
    const float* wqkvdw = (const float*)d_in[3];
    const float* wproj  = (const float*)d_in[4];
    const float* temp   = (const float*)d_in[5];
    const float* resc   = (const float*)d_in[6];
    float* out = (float*)d_out;

    char* ws = (char*)d_ws;
    ushort_t* qkvraw = (ushort_t*)ws;                              // 150,994,944 B (bf16)
    ushort_t* qkvd   = (ushort_t*)(ws + 150994944);                // 150,994,944 B (bf16)
    char* small = ws + 301989888;
    float* var  = (float*)small;                                   // 6,144 B
    float* ssq  = (float*)(small + 6144);                          // 12,288 B
    float* G    = (float*)(small + 6144 + 12288);                  // 147,456 B
    ushort_t* Weff = (ushort_t*)(small + 6144 + 12288 + 147456);   // 589,824 B

    (void)hipMemsetAsync(G, 0, 147456, stream);
    k_dwvar<<<dim3(1536), dim3(256), 0, stream>>>(x, wdw, var);
    k_gemm<1, 1, 0><<<dim3(128, 9, 8), dim3(256), 0, stream>>>(wqkv, 0L, x, 3145728L, qkvraw, 9437184L, 192);
    k_dwqkv<<<dim3(4608), dim3(256), 0, stream>>>(qkvraw, wqkvdw, qkvd, ssq);
    k_gram<<<dim3(8, 64), dim3(256), 0, stream>>>(qkvd, G);
    k_smweff<<<dim3(8), dim3(256), 0, stream>>>(G, ssq, var, wproj, temp, resc, Weff);
    k_gemm<0, 0, 1><<<dim3(128, 3, 8), dim3(256), 0, stream>>>(Weff, 36864L, qkvd + (size_t)384 * HW, 9437184L, out, 3145728L, 192);
}